// Round 3
// baseline (1518.168 us; speedup 1.0000x reference)
//
#include <hip/hip_runtime.h>
#include <hip/hip_bf16.h>
#include <math.h>

// Problem constants
#define LYRS 4
#define BB   2
#define SS   2048
#define HH   1024
#define NHD  16
#define HDD  64
#define FFN_ 4096
#define BS   (BB*SS)          // 4096 rows
#define EPS_ 1e-5f

typedef __attribute__((ext_vector_type(8))) __bf16 bf16x8;
typedef __attribute__((ext_vector_type(4))) __bf16 bf16x4;
typedef __attribute__((ext_vector_type(4))) float f32x4;
typedef __attribute__((address_space(1))) void* gas_t;
typedef __attribute__((address_space(3))) void* las_t;

__device__ inline void async16(void* lds, const void* g) {
    __builtin_amdgcn_global_load_lds((gas_t)g, (las_t)lds, 16, 0, 0);
}

__device__ inline void storev(float* p, float v) { *p = v; }
__device__ inline void storev(__hip_bfloat16* p, float v) { *p = __float2bfloat16(v); }

// ---------------- LayerNorm: one block (256 thr) per row of H=1024 ----------
template <typename OutT>
__global__ void ln_k(const float* __restrict__ x, const float* __restrict__ g,
                     const float* __restrict__ b, OutT* __restrict__ y) {
    const int row = blockIdx.x;
    const int tid = threadIdx.x;           // 256
    const float* xr = x + (size_t)row * HH;

    float v[4];
    float s = 0.f, s2 = 0.f;
#pragma unroll
    for (int i = 0; i < 4; ++i) {
        v[i] = xr[tid + i * 256];
        s  += v[i];
        s2 += v[i] * v[i];
    }
#pragma unroll
    for (int o = 1; o < 64; o <<= 1) {
        s  += __shfl_xor(s,  o);
        s2 += __shfl_xor(s2, o);
    }
    __shared__ float sh[8];
    const int wave = tid >> 6, lane = tid & 63;
    if (lane == 0) { sh[wave] = s; sh[4 + wave] = s2; }
    __syncthreads();
    if (tid == 0) {
        float ts  = sh[0] + sh[1] + sh[2] + sh[3];
        float ts2 = sh[4] + sh[5] + sh[6] + sh[7];
        float mu  = ts * (1.f / HH);
        sh[0] = mu;
        sh[1] = ts2 * (1.f / HH) - mu * mu;   // var
    }
    __syncthreads();
    const float mu   = sh[0];
    const float rstd = rsqrtf(sh[1] + EPS_);
#pragma unroll
    for (int i = 0; i < 4; ++i) {
        int c = tid + i * 256;
        storev(&y[(size_t)row * HH + c], (v[i] - mu) * rstd * g[c] + b[c]);
    }
}

// ---------------- transpose + cast: W[K,N] f32 -> WT[N,K] bf16 --------------
__global__ __launch_bounds__(256) void transpose_cast(const float* __restrict__ W,
                                                      __hip_bfloat16* __restrict__ WT,
                                                      int K, int N) {
    __shared__ float t[32][33];
    const int n0 = blockIdx.x * 32, k0 = blockIdx.y * 32;
    const int tx = threadIdx.x & 31, ty8 = threadIdx.x >> 5;   // ty8: 0..7
#pragma unroll
    for (int i = 0; i < 4; ++i) {
        int k = ty8 + i * 8;
        t[k][tx] = W[(size_t)(k0 + k) * N + n0 + tx];
    }
    __syncthreads();
#pragma unroll
    for (int i = 0; i < 4; ++i) {
        int n = ty8 + i * 8;
        WT[(size_t)(n0 + n) * K + k0 + tx] = __float2bfloat16(t[tx][n]);
    }
}

// ---------------- 128x128 bf16 MFMA GEMM (4 waves, 2-phase dbuf) ------------
// Used for qkv (3 blocks/CU) and proj (split-K=2 -> 2 blocks/CU).
// SPLITK>1: fp32 partials atomicAdd'ed into C (caller: C holds residual).
template <bool GELU, bool RES, int SPLITK, typename OutT>
__global__ __launch_bounds__(256) void gemm_bf16(
    const __hip_bfloat16* __restrict__ A,    // [M,K] row-major
    const __hip_bfloat16* __restrict__ BT,   // [N,K] row-major (= B^T)
    const float* __restrict__ R,             // residual [M,N] fp32 (or null)
    OutT* __restrict__ C,                    // [M,N]
    int M, int N, int K)
{
    __shared__ unsigned short As[2][128 * 32];
    __shared__ unsigned short Bs[2][128 * 32];

    const int tid  = threadIdx.x;
    const int lane = tid & 63;
    const int wv   = tid >> 6;               // 0..3
    const int wy   = wv >> 1, wx = wv & 1;   // 2x2 wave grid (64x64 each)
    const int nby  = M >> 7;                 // 32
    const int tiles = nby * (N >> 7);
    const int ks   = blockIdx.x / tiles;     // K-slice (0 if SPLITK==1)
    const int rem  = blockIdx.x % tiles;
    const int by   = rem % nby;
    const int bx   = rem / nby;
    const int row0 = by * 128;
    const int col0 = bx * 128;
    const int lm   = lane & 15;
    const int kq   = lane >> 4;

    const int Kslice = K / SPLITK;
    const int kbeg   = ks * Kslice;
    const int nsteps = Kslice >> 5;

    const unsigned short* Ag = (const unsigned short*)A;
    const unsigned short* Bg = (const unsigned short*)BT;

    const int li0 = tid, li1 = 256 + tid;
    const int r0 = li0 >> 2, c0 = (li0 & 3) << 3;
    const int r1 = li1 >> 2, c1 = (li1 & 3) << 3;
    const unsigned short* Ag0 = Ag + (size_t)(row0 + r0) * K + c0;
    const unsigned short* Ag1 = Ag + (size_t)(row0 + r1) * K + c1;
    const unsigned short* Bg0 = Bg + (size_t)(col0 + r0) * K + c0;
    const unsigned short* Bg1 = Bg + (size_t)(col0 + r1) * K + c1;

    auto stage = [&](int buf, int k) {
        async16(&As[buf][li0 * 8], Ag0 + k);
        async16(&As[buf][li1 * 8], Ag1 + k);
        async16(&Bs[buf][li0 * 8], Bg0 + k);
        async16(&Bs[buf][li1 * 8], Bg1 + k);
    };

    f32x4 acc[4][4] = {};

    stage(0, kbeg);
    __syncthreads();                         // tile 0 ready

    for (int s = 0; s < nsteps; ++s) {
        const int buf = s & 1;
        if (s + 1 < nsteps) stage(buf ^ 1, kbeg + ((s + 1) << 5));

        bf16x8 af[4], bfr[4];
#pragma unroll
        for (int i = 0; i < 4; ++i)
            af[i] = *(const bf16x8*)&As[buf][(wy * 64 + i * 16 + lm) * 32 + kq * 8];
#pragma unroll
        for (int j = 0; j < 4; ++j)
            bfr[j] = *(const bf16x8*)&Bs[buf][(wx * 64 + j * 16 + lm) * 32 + kq * 8];
#pragma unroll
        for (int i = 0; i < 4; ++i)
#pragma unroll
            for (int j = 0; j < 4; ++j)
                acc[i][j] = __builtin_amdgcn_mfma_f32_16x16x32_bf16(
                    af[i], bfr[j], acc[i][j], 0, 0, 0);

        __syncthreads();   // my reads done + next tile landed
    }

#pragma unroll
    for (int i = 0; i < 4; ++i) {
#pragma unroll
        for (int j = 0; j < 4; ++j) {
            int gc = col0 + wx * 64 + j * 16 + lm;
#pragma unroll
            for (int r = 0; r < 4; ++r) {
                int gr = row0 + wy * 64 + i * 16 + kq * 4 + r;
                float v = acc[i][j][r];
                if constexpr (SPLITK > 1) {
                    atomicAdd((float*)&C[(size_t)gr * N + gc], v);
                } else {
                    if (RES)  v += R[(size_t)gr * N + gc];
                    if (GELU) v = 0.5f * v * (1.0f + erff(v * 0.70710678118654752f));
                    storev(&C[(size_t)gr * N + gc], v);
                }
            }
        }
    }
}

// ---------------- 256x256 bf16 MFMA GEMM (8 waves, 2-phase dbuf) ------------
// Arithmetic intensity 128 FLOP/staged-byte (2x the 128^2 tile): per-step
// MFMA work (~1250 SIMD-cy) exceeds global-load latency, so the 2-phase
// syncthreads drain is covered. BK=32, 64 KB LDS, 1 block/CU, 2 waves/SIMD.
// LDS chunk swizzle g(r)=(r>>1)&3 (rule-21 pattern c: linear gload_lds dest,
// inverse-swizzled global source, swizzled ds_read) -> frag reads 2-way = free.
// SPLITK>1: fp32 partials atomicAdd'ed into C (caller: C holds residual).
template <bool GELU, bool RES, int SPLITK, typename OutT>
__global__ __launch_bounds__(512, 2) void gemm256(
    const __hip_bfloat16* __restrict__ A,    // [M,K] row-major
    const __hip_bfloat16* __restrict__ BT,   // [N,K] row-major (= B^T)
    const float* __restrict__ R,             // residual [M,N] fp32 (or null)
    OutT* __restrict__ C,                    // [M,N]
    int M, int N, int K)
{
    __shared__ unsigned short As[2][256 * 32];
    __shared__ unsigned short Bs[2][256 * 32];

    const int tid  = threadIdx.x;            // 0..511
    const int lane = tid & 63;
    const int wv   = tid >> 6;               // 0..7
    const int wy   = wv >> 2;                // 0..1 : 128-row half
    const int wx   = wv & 3;                 // 0..3 : 64-col quarter
    const int nby  = M >> 8;
    const int tiles = nby * (N >> 8);
    const int ks   = blockIdx.x / tiles;
    const int rem  = blockIdx.x % tiles;
    const int by   = rem % nby;
    const int bx   = rem / nby;
    const int row0 = by * 256;
    const int col0 = bx * 256;
    const int lm   = lane & 15;
    const int kq   = lane >> 4;

    const int Kslice = K / SPLITK;
    const int kbeg   = ks * Kslice;
    const int nsteps = Kslice >> 5;          // BK=32

    const unsigned short* Ag = (const unsigned short*)A;
    const unsigned short* Bg = (const unsigned short*)BT;

    // staging: 2 iters x 512 thr x 16B per matrix = 16KB (256 rows x 32 cols)
    // LDS[r][chunk c] = global[r][c ^ g(r)], g(r) = (r>>1)&3
    const int liA = tid, liB = 512 + tid;
    const int ra = liA >> 2, rb = liB >> 2;
    const int ca = ((liA & 3) ^ ((ra >> 1) & 3)) << 3;   // swizzled src chunk
    const int cb = ((liB & 3) ^ ((rb >> 1) & 3)) << 3;
    const unsigned short* Ag0 = Ag + (size_t)(row0 + ra) * K + ca;
    const unsigned short* Ag1 = Ag + (size_t)(row0 + rb) * K + cb;
    const unsigned short* Bg0 = Bg + (size_t)(col0 + ra) * K + ca;
    const unsigned short* Bg1 = Bg + (size_t)(col0 + rb) * K + cb;

    auto stage = [&](int buf, int k) {
        async16(&As[buf][liA * 8], Ag0 + k);
        async16(&As[buf][liB * 8], Ag1 + k);
        async16(&Bs[buf][liA * 8], Bg0 + k);
        async16(&Bs[buf][liB * 8], Bg1 + k);
    };

    // frag-read chunk: want chunk kq of row -> read chunk kq ^ g(row);
    // row&15 == lm for all frag rows, so g(row) = (lm>>1)&3.
    const int rdoff = ((kq ^ ((lm >> 1) & 3)) << 3);

    f32x4 acc[8][4] = {};

    stage(0, kbeg);
    __syncthreads();

    for (int s = 0; s < nsteps; ++s) {
        const int buf = s & 1;
        if (s + 1 < nsteps) stage(buf ^ 1, kbeg + ((s + 1) << 5));

        bf16x8 af[8], bfr[4];
#pragma unroll
        for (int i = 0; i < 8; ++i)
            af[i] = *(const bf16x8*)&As[buf][(wy * 128 + i * 16 + lm) * 32 + rdoff];
#pragma unroll
        for (int j = 0; j < 4; ++j)
            bfr[j] = *(const bf16x8*)&Bs[buf][(wx * 64 + j * 16 + lm) * 32 + rdoff];
#pragma unroll
        for (int i = 0; i < 8; ++i)
#pragma unroll
            for (int j = 0; j < 4; ++j)
                acc[i][j] = __builtin_amdgcn_mfma_f32_16x16x32_bf16(
                    af[i], bfr[j], acc[i][j], 0, 0, 0);

        __syncthreads();
    }

#pragma unroll
    for (int i = 0; i < 8; ++i) {
#pragma unroll
        for (int j = 0; j < 4; ++j) {
            int gc = col0 + wx * 64 + j * 16 + lm;
#pragma unroll
            for (int r = 0; r < 4; ++r) {
                int gr = row0 + wy * 128 + i * 16 + kq * 4 + r;
                float v = acc[i][j][r];
                if constexpr (SPLITK > 1) {
                    atomicAdd((float*)&C[(size_t)gr * N + gc], v);
                } else {
                    if (RES)  v += R[(size_t)gr * N + gc];
                    if (GELU) v = 0.5f * v * (1.0f + erff(v * 0.70710678118654752f));
                    storev(&C[(size_t)gr * N + gc], v);
                }
            }
        }
    }
}

// ---------------- MFMA causal flash attention (double-buffered) -------------
__global__ __launch_bounds__(256) void attn_fa3(const __bf16* __restrict__ qkv,
                                                __bf16* __restrict__ out) {
    __shared__ __bf16 Ks[2][64 * 72];       // K[key][d], stride 72
    __shared__ __bf16 Vt[2][64 * 72];       // V^T[d][key], stride 72
    __shared__ __bf16 Ps[4][2][16 * 72];    // per wave/slab: P[q][key]

    const int tid  = threadIdx.x;
    const int lane = tid & 63;
    const int w    = tid >> 6;              // wave 0..3
    const int lm   = lane & 15;
    const int kq   = lane >> 4;

    const int x  = blockIdx.x;
    const int bh = x & 31;
    const int h  = bh & 15;
    const int b  = bh >> 4;
    const int a  = (x >> 5) & 7;
    const int qt = (x & 256) ? (15 - a) : a;
    const int q0 = qt * 128;

    const size_t rs   = 3 * HH;
    const size_t base = (size_t)b * SS * rs + (size_t)h * HDD;

    const int krow0 = tid >> 3,        kc0 = (tid & 7) << 3;          // it=0
    const int krow1 = (256 + tid) >> 3, kc1 = ((256 + tid) & 7) << 3; // it=1
    const int vkey  = tid & 63;
    const int vcb0  = (tid >> 6) << 3, vcb1 = ((256 + tid) >> 6) << 3;

    bf16x8 qf[2][2];
#pragma unroll
    for (int s = 0; s < 2; ++s)
#pragma unroll
        for (int kh = 0; kh < 2; ++kh) {
            bf16x8 t = *(const bf16x8*)&qkv[base +
                (size_t)(q0 + w * 32 + s * 16 + lm) * rs + kh * 32 + kq * 8];
#pragma unroll
            for (int j = 0; j < 8; ++j) t[j] = (__bf16)((float)t[j] * 0.125f);
            qf[s][kh] = t;
        }

    f32x4 ot[2][4] = {};
    float m_i[2] = {-INFINITY, -INFINITY};
    float l_i[2] = {0.f, 0.f};

    const int qmax_w = q0 + w * 32 + 31;
    const int ktmax  = (q0 + 127) >> 6;     // 2qt+1

    bf16x8 kr0, kr1, vr0, vr1;
    {
        const int k0 = 0;
        kr0 = *(const bf16x8*)&qkv[base + (size_t)(k0 + krow0) * rs + HH + kc0];
        kr1 = *(const bf16x8*)&qkv[base + (size_t)(k0 + krow1) * rs + HH + kc1];
        vr0 = *(const bf16x8*)&qkv[base + (size_t)(k0 + vkey) * rs + 2 * HH + vcb0];
        vr1 = *(const bf16x8*)&qkv[base + (size_t)(k0 + vkey) * rs + 2 * HH + vcb1];
        *(bf16x8*)&Ks[0][krow0 * 72 + kc0] = kr0;
        *(bf16x8*)&Ks[0][krow1 * 72 + kc1] = kr1;
#pragma unroll
        for (int j = 0; j < 8; ++j) Vt[0][(vcb0 + j) * 72 + vkey] = vr0[j];
#pragma unroll
        for (int j = 0; j < 8; ++j) Vt[0][(vcb1 + j) * 72 + vkey] = vr1[j];
    }
    __syncthreads();

    for (int kt = 0; kt <= ktmax; ++kt) {
        const int k0  = kt << 6;
        const int buf = kt & 1;

        if (kt < ktmax) {
            const int kn = k0 + 64;
            kr0 = *(const bf16x8*)&qkv[base + (size_t)(kn + krow0) * rs + HH + kc0];
            kr1 = *(const bf16x8*)&qkv[base + (size_t)(kn + krow1) * rs + HH + kc1];
            vr0 = *(const bf16x8*)&qkv[base + (size_t)(kn + vkey) * rs + 2 * HH + vcb0];
            vr1 = *(const bf16x8*)&qkv[base + (size_t)(kn + vkey) * rs + 2 * HH + vcb1];
        }

        if (k0 <= qmax_w) {
#pragma unroll
            for (int s = 0; s < 2; ++s) {
                f32x4 st[4] = {};
#pragma unroll
                for (int kh = 0; kh < 2; ++kh)
#pragma unroll
                    for (int m = 0; m < 4; ++m) {
                        bf16x8 kf = *(const bf16x8*)&Ks[buf][(m * 16 + lm) * 72 + kh * 32 + kq * 8];
                        st[m] = __builtin_amdgcn_mfma_f32_16x16x32_bf16(
                            kf, qf[s][kh], st[m], 0, 0, 0);
                    }

                const int qg = q0 + w * 32 + s * 16 + lm;
                if (k0 + 63 > q0 + w * 32 + s * 16) {
#pragma unroll
                    for (int m = 0; m < 4; ++m) {
                        int keyb = k0 + m * 16 + kq * 4;
#pragma unroll
                        for (int r = 0; r < 4; ++r)
                            if (keyb + r > qg) st[m][r] = -INFINITY;
                    }
                }

                float mloc = -INFINITY;
#pragma unroll
                for (int m = 0; m < 4; ++m)
#pragma unroll
                    for (int r = 0; r < 4; ++r) mloc = fmaxf(mloc, st[m][r]);
                mloc = fmaxf(mloc, __shfl_xor(mloc, 16));
                mloc = fmaxf(mloc, __shfl_xor(mloc, 32));
                float mn    = fmaxf(m_i[s], mloc);
                float alpha = __expf(m_i[s] - mn);
                m_i[s] = mn;

                float sum = 0.f;
#pragma unroll
                for (int m = 0; m < 4; ++m) {
                    bf16x4 pb;
#pragma unroll
                    for (int r = 0; r < 4; ++r) {
                        float p = __expf(st[m][r] - mn);
                        sum += p;
                        pb[r] = (__bf16)p;
                    }
                    *(bf16x4*)&Ps[w][s][lm * 72 + m * 16 + kq * 4] = pb;
                }
                sum += __shfl_xor(sum, 16);
                sum += __shfl_xor(sum, 32);
                l_i[s] = l_i[s] * alpha + sum;

#pragma unroll
                for (int dt = 0; dt < 4; ++dt) ot[s][dt] *= alpha;

#pragma unroll
                for (int kh = 0; kh < 2; ++kh) {
                    bf16x8 pf = *(const bf16x8*)&Ps[w][s][lm * 72 + kh * 32 + kq * 8];
#pragma unroll
                    for (int dt = 0; dt < 4; ++dt) {
                        bf16x8 vf = *(const bf16x8*)&Vt[buf][(dt * 16 + lm) * 72 + kh * 32 + kq * 8];
                        ot[s][dt] = __builtin_amdgcn_mfma_f32_16x16x32_bf16(
                            vf, pf, ot[s][dt], 0, 0, 0);
                    }
                }
            }
        }

        if (kt < ktmax) {
            const int nb = buf ^ 1;
            *(bf16x8*)&Ks[nb][krow0 * 72 + kc0] = kr0;
            *(bf16x8*)&Ks[nb][krow1 * 72 + kc1] = kr1;
#pragma unroll
            for (int j = 0; j < 8; ++j) Vt[nb][(vcb0 + j) * 72 + vkey] = vr0[j];
#pragma unroll
            for (int j = 0; j < 8; ++j) Vt[nb][(vcb1 + j) * 72 + vkey] = vr1[j];
            __syncthreads();
        }
    }

#pragma unroll
    for (int s = 0; s < 2; ++s) {
        float inv = 1.f / l_i[s];
        int qg = q0 + w * 32 + s * 16 + lm;
#pragma unroll
        for (int dt = 0; dt < 4; ++dt) {
            bf16x4 ob;
#pragma unroll
            for (int r = 0; r < 4; ++r) ob[r] = (__bf16)(ot[s][dt][r] * inv);
            *(bf16x4*)&out[(size_t)(b * SS + qg) * HH + h * HDD + dt * 16 + kq * 4] = ob;
        }
    }
}

// ---------------------------------------------------------------------------
extern "C" void kernel_launch(void* const* d_in, const int* in_sizes, int n_in,
                              void* d_out, int out_size, void* d_ws, size_t ws_size,
                              hipStream_t stream) {
    const float* hidden = (const float*)d_in[0];
    const float* ln1_g  = (const float*)d_in[1];
    const float* ln1_b  = (const float*)d_in[2];
    const float* Wqkv   = (const float*)d_in[3];
    const float* Wproj  = (const float*)d_in[4];
    const float* ln2_g  = (const float*)d_in[5];
    const float* ln2_b  = (const float*)d_in[6];
    const float* Wfc1   = (const float*)d_in[7];
    const float* Wfc2   = (const float*)d_in[8];
    const float* lnf_g  = (const float*)d_in[9];
    const float* lnf_b  = (const float*)d_in[10];

    float* x = (float*)d_out;              // residual stream (fp32) in d_out

    char* p = (char*)d_ws;
    __hip_bfloat16* hbuf  = (__hip_bfloat16*)p; p += (size_t)BS * HH * 2;
    __hip_bfloat16* qkvb  = (__hip_bfloat16*)p; p += (size_t)BS * 3 * HH * 2;
    __hip_bfloat16* attnb = (__hip_bfloat16*)p; p += (size_t)BS * HH * 2;
    __hip_bfloat16* ffnb  = (__hip_bfloat16*)p; p += (size_t)BS * FFN_ * 2;
    __hip_bfloat16* wqkvT = (__hip_bfloat16*)p; p += (size_t)3 * HH * HH * 2;
    __hip_bfloat16* wprojT= (__hip_bfloat16*)p; p += (size_t)HH * HH * 2;
    __hip_bfloat16* wfc1T = (__hip_bfloat16*)p; p += (size_t)FFN_ * HH * 2;
    __hip_bfloat16* wfc2T = (__hip_bfloat16*)p; p += (size_t)HH * FFN_ * 2;

    hipMemcpyAsync(x, hidden, (size_t)BS * HH * sizeof(float),
                   hipMemcpyDeviceToDevice, stream);

    const int NBY = BS / 128;   // 32

    for (int lyr = 0; lyr < LYRS; ++lyr) {
        transpose_cast<<<dim3(3 * HH / 32, HH / 32), 256, 0, stream>>>(
            Wqkv + (size_t)lyr * HH * 3 * HH, wqkvT, HH, 3 * HH);
        transpose_cast<<<dim3(HH / 32, HH / 32), 256, 0, stream>>>(
            Wproj + (size_t)lyr * HH * HH, wprojT, HH, HH);
        transpose_cast<<<dim3(FFN_ / 32, HH / 32), 256, 0, stream>>>(
            Wfc1 + (size_t)lyr * HH * FFN_, wfc1T, HH, FFN_);
        transpose_cast<<<dim3(HH / 32, FFN_ / 32), 256, 0, stream>>>(
            Wfc2 + (size_t)lyr * FFN_ * HH, wfc2T, FFN_, HH);

        ln_k<__hip_bfloat16><<<BS, 256, 0, stream>>>(
            x, ln1_g + lyr * HH, ln1_b + lyr * HH, hbuf);
        // qkv: 128^2, 768 blocks (3 blocks/CU)
        gemm_bf16<false, false, 1, __hip_bfloat16>
            <<<(3 * HH / 128) * NBY, 256, 0, stream>>>(
            hbuf, wqkvT, nullptr, qkvb, BS, 3 * HH, HH);
        attn_fa3<<<512, 256, 0, stream>>>((const __bf16*)qkvb, (__bf16*)attnb);
        // proj: 128^2 split-K=2 (512 blocks); x holds residual, atomics add in
        gemm_bf16<false, false, 2, float>
            <<<(HH / 128) * NBY * 2, 256, 0, stream>>>(
            attnb, wprojT, nullptr, x, BS, HH, HH);
        ln_k<__hip_bfloat16><<<BS, 256, 0, stream>>>(
            x, ln2_g + lyr * HH, ln2_b + lyr * HH, hbuf);
        // fc1: 256^2 tile, grid 16x16 = 256 blocks (1/CU, 8 waves)
        gemm256<true, false, 1, __hip_bfloat16>
            <<<(BS / 256) * (FFN_ / 256), 512, 0, stream>>>(
            hbuf, wfc1T, nullptr, ffnb, BS, FFN_, HH);
        // fc2: 256^2 split-K=4 -> 64*4 = 256 blocks; atomics into x
        gemm256<false, false, 4, float>
            <<<(BS / 256) * (HH / 256) * 4, 512, 0, stream>>>(
            ffnb, wfc2T, nullptr, x, BS, HH, FFN_);
    }
    ln_k<float><<<BS, 256, 0, stream>>>(x, lnf_g, lnf_b, x);
}

// Round 4
// 1316.536 us; speedup vs baseline: 1.1532x; 1.1532x over previous
//
#include <hip/hip_runtime.h>
#include <hip/hip_bf16.h>
#include <math.h>

// Problem constants
#define LYRS 4
#define BB   2
#define SS   2048
#define HH   1024
#define NHD  16
#define HDD  64
#define FFN_ 4096
#define BS   (BB*SS)          // 4096 rows
#define EPS_ 1e-5f

typedef __attribute__((ext_vector_type(8))) __bf16 bf16x8;
typedef __attribute__((ext_vector_type(4))) __bf16 bf16x4;
typedef __attribute__((ext_vector_type(4))) float f32x4;
typedef __attribute__((address_space(1))) void* gas_t;
typedef __attribute__((address_space(3))) void* las_t;

__device__ inline void async16(void* lds, const void* g) {
    __builtin_amdgcn_global_load_lds((gas_t)g, (las_t)lds, 16, 0, 0);
}

__device__ inline void storev(float* p, float v) { *p = v; }
__device__ inline void storev(__hip_bfloat16* p, float v) { *p = __float2bfloat16(v); }

__device__ inline void store4(float* p, float a, float b, float c, float d) {
    *(float4*)p = make_float4(a, b, c, d);
}
__device__ inline void store4(__hip_bfloat16* p, float a, float b, float c, float d) {
    bf16x4 t; t[0] = (__bf16)a; t[1] = (__bf16)b; t[2] = (__bf16)c; t[3] = (__bf16)d;
    *(bf16x4*)p = t;
}

// ---------------- LayerNorm: one WAVE per row of H=1024 ---------------------
// 4 waves/block, no LDS, no barriers; float4 loads; shfl-tree reduction.
template <typename OutT>
__global__ __launch_bounds__(256) void ln_w(const float* __restrict__ x,
                                            const float* __restrict__ g,
                                            const float* __restrict__ b,
                                            OutT* __restrict__ y) {
    const int row  = blockIdx.x * 4 + (threadIdx.x >> 6);
    const int lane = threadIdx.x & 63;
    const float4* xr = (const float4*)(x + (size_t)row * HH);

    float4 v[4];
    float s = 0.f, s2 = 0.f;
#pragma unroll
    for (int i = 0; i < 4; ++i) {
        v[i] = xr[lane + i * 64];
        s  += v[i].x + v[i].y + v[i].z + v[i].w;
        s2 += v[i].x * v[i].x + v[i].y * v[i].y + v[i].z * v[i].z + v[i].w * v[i].w;
    }
#pragma unroll
    for (int o = 1; o < 64; o <<= 1) {
        s  += __shfl_xor(s,  o);
        s2 += __shfl_xor(s2, o);
    }
    const float mu   = s * (1.f / HH);
    const float rstd = rsqrtf(s2 * (1.f / HH) - mu * mu + EPS_);
#pragma unroll
    for (int i = 0; i < 4; ++i) {
        const int c = (lane + i * 64) * 4;
        const float4 gv = *(const float4*)&g[c];
        const float4 bv = *(const float4*)&b[c];
        store4(&y[(size_t)row * HH + c],
               (v[i].x - mu) * rstd * gv.x + bv.x,
               (v[i].y - mu) * rstd * gv.y + bv.y,
               (v[i].z - mu) * rstd * gv.z + bv.z,
               (v[i].w - mu) * rstd * gv.w + bv.w);
    }
}

// ---------------- batched transpose+cast: all 4 weights of one layer --------
// W[K,N] f32 -> WT[N,K] bf16 for {Wqkv, Wproj, Wfc1, Wfc2} in ONE launch.
__global__ __launch_bounds__(256) void transpose_all(
    const float* __restrict__ Wqkv_l, const float* __restrict__ Wproj_l,
    const float* __restrict__ Wfc1_l, const float* __restrict__ Wfc2_l,
    __hip_bfloat16* __restrict__ wqkvT, __hip_bfloat16* __restrict__ wprojT,
    __hip_bfloat16* __restrict__ wfc1T, __hip_bfloat16* __restrict__ wfc2T)
{
    __shared__ float t[32][33];
    int tb = blockIdx.x;
    const float* W; __hip_bfloat16* WT; int K, N, nx;
    if (tb < 3072)      {            W = Wqkv_l;  WT = wqkvT;  K = HH;   N = 3 * HH; nx = 96;  }
    else if (tb < 4096) { tb -= 3072; W = Wproj_l; WT = wprojT; K = HH;   N = HH;     nx = 32;  }
    else if (tb < 8192) { tb -= 4096; W = Wfc1_l;  WT = wfc1T;  K = HH;   N = FFN_;   nx = 128; }
    else                { tb -= 8192; W = Wfc2_l;  WT = wfc2T;  K = FFN_; N = HH;     nx = 32;  }
    const int n0 = (tb % nx) * 32, k0 = (tb / nx) * 32;
    const int tx = threadIdx.x & 31, ty8 = threadIdx.x >> 5;
#pragma unroll
    for (int i = 0; i < 4; ++i) {
        int k = ty8 + i * 8;
        t[k][tx] = W[(size_t)(k0 + k) * N + n0 + tx];
    }
    __syncthreads();
#pragma unroll
    for (int i = 0; i < 4; ++i) {
        int n = ty8 + i * 8;
        WT[(size_t)(n0 + n) * K + k0 + tx] = __float2bfloat16(t[tx][n]);
    }
}

// ---------------- 128x128 bf16 MFMA GEMM (4 waves, 2-phase dbuf) ------------
// Round-1-proven structure, byte-identical K-loop.
// SPLITK>1: fp32 partials atomicAdd'ed into C (caller: C holds residual).
template <bool GELU, bool RES, int SPLITK, typename OutT>
__global__ __launch_bounds__(256) void gemm_bf16(
    const __hip_bfloat16* __restrict__ A,    // [M,K] row-major
    const __hip_bfloat16* __restrict__ BT,   // [N,K] row-major (= B^T)
    const float* __restrict__ R,             // residual [M,N] fp32 (or null)
    OutT* __restrict__ C,                    // [M,N]
    int M, int N, int K)
{
    __shared__ unsigned short As[2][128 * 32];
    __shared__ unsigned short Bs[2][128 * 32];

    const int tid  = threadIdx.x;
    const int lane = tid & 63;
    const int wv   = tid >> 6;               // 0..3
    const int wy   = wv >> 1, wx = wv & 1;   // 2x2 wave grid (64x64 each)
    const int nby  = M >> 7;                 // 32
    const int tiles = nby * (N >> 7);
    const int ks   = blockIdx.x / tiles;     // K-slice (0 if SPLITK==1)
    const int rem  = blockIdx.x % tiles;
    const int by   = rem % nby;
    const int bx   = rem / nby;
    const int row0 = by * 128;
    const int col0 = bx * 128;
    const int lm   = lane & 15;
    const int kq   = lane >> 4;

    const int Kslice = K / SPLITK;
    const int kbeg   = ks * Kslice;
    const int nsteps = Kslice >> 5;

    const unsigned short* Ag = (const unsigned short*)A;
    const unsigned short* Bg = (const unsigned short*)BT;

    const int li0 = tid, li1 = 256 + tid;
    const int r0 = li0 >> 2, c0 = (li0 & 3) << 3;
    const int r1 = li1 >> 2, c1 = (li1 & 3) << 3;
    const unsigned short* Ag0 = Ag + (size_t)(row0 + r0) * K + c0;
    const unsigned short* Ag1 = Ag + (size_t)(row0 + r1) * K + c1;
    const unsigned short* Bg0 = Bg + (size_t)(col0 + r0) * K + c0;
    const unsigned short* Bg1 = Bg + (size_t)(col0 + r1) * K + c1;

    auto stage = [&](int buf, int k) {
        async16(&As[buf][li0 * 8], Ag0 + k);
        async16(&As[buf][li1 * 8], Ag1 + k);
        async16(&Bs[buf][li0 * 8], Bg0 + k);
        async16(&Bs[buf][li1 * 8], Bg1 + k);
    };

    f32x4 acc[4][4] = {};

    stage(0, kbeg);
    __syncthreads();                         // tile 0 ready

    for (int s = 0; s < nsteps; ++s) {
        const int buf = s & 1;
        if (s + 1 < nsteps) stage(buf ^ 1, kbeg + ((s + 1) << 5));

        bf16x8 af[4], bfr[4];
#pragma unroll
        for (int i = 0; i < 4; ++i)
            af[i] = *(const bf16x8*)&As[buf][(wy * 64 + i * 16 + lm) * 32 + kq * 8];
#pragma unroll
        for (int j = 0; j < 4; ++j)
            bfr[j] = *(const bf16x8*)&Bs[buf][(wx * 64 + j * 16 + lm) * 32 + kq * 8];
#pragma unroll
        for (int i = 0; i < 4; ++i)
#pragma unroll
            for (int j = 0; j < 4; ++j)
                acc[i][j] = __builtin_amdgcn_mfma_f32_16x16x32_bf16(
                    af[i], bfr[j], acc[i][j], 0, 0, 0);

        __syncthreads();   // my reads done + next tile landed
    }

#pragma unroll
    for (int i = 0; i < 4; ++i) {
#pragma unroll
        for (int j = 0; j < 4; ++j) {
            int gc = col0 + wx * 64 + j * 16 + lm;
#pragma unroll
            for (int r = 0; r < 4; ++r) {
                int gr = row0 + wy * 64 + i * 16 + kq * 4 + r;
                float v = acc[i][j][r];
                if constexpr (SPLITK > 1) {
                    atomicAdd((float*)&C[(size_t)gr * N + gc], v);
                } else {
                    if (RES)  v += R[(size_t)gr * N + gc];
                    if (GELU) v = 0.5f * v * (1.0f + erff(v * 0.70710678118654752f));
                    storev(&C[(size_t)gr * N + gc], v);
                }
            }
        }
    }
}

// ---------------- MFMA causal flash attention (double-buffered) -------------
// Block = 128 queries x 1 head, 256 thr (4 waves x 2 slabs of 16 q).
// S^T = K·Q^T; softmax over MFMA rows (keys). P^T via LDS; O^T = V^T·P^T.
// setprio(1) around both MFMA clusters (T5: measured +4-7% on attn, m191).
__global__ __launch_bounds__(256) void attn_fa3(const __bf16* __restrict__ qkv,
                                                __bf16* __restrict__ out) {
    __shared__ __bf16 Ks[2][64 * 72];       // K[key][d], stride 72
    __shared__ __bf16 Vt[2][64 * 72];       // V^T[d][key], stride 72
    __shared__ __bf16 Ps[4][2][16 * 72];    // per wave/slab: P[q][key]

    const int tid  = threadIdx.x;
    const int lane = tid & 63;
    const int w    = tid >> 6;              // wave 0..3
    const int lm   = lane & 15;
    const int kq   = lane >> 4;

    const int x  = blockIdx.x;
    const int bh = x & 31;
    const int h  = bh & 15;
    const int b  = bh >> 4;
    const int a  = (x >> 5) & 7;
    const int qt = (x & 256) ? (15 - a) : a;
    const int q0 = qt * 128;

    const size_t rs   = 3 * HH;
    const size_t base = (size_t)b * SS * rs + (size_t)h * HDD;

    const int krow0 = tid >> 3,        kc0 = (tid & 7) << 3;          // it=0
    const int krow1 = (256 + tid) >> 3, kc1 = ((256 + tid) & 7) << 3; // it=1
    const int vkey  = tid & 63;
    const int vcb0  = (tid >> 6) << 3, vcb1 = ((256 + tid) >> 6) << 3;

    bf16x8 qf[2][2];
#pragma unroll
    for (int s = 0; s < 2; ++s)
#pragma unroll
        for (int kh = 0; kh < 2; ++kh) {
            bf16x8 t = *(const bf16x8*)&qkv[base +
                (size_t)(q0 + w * 32 + s * 16 + lm) * rs + kh * 32 + kq * 8];
#pragma unroll
            for (int j = 0; j < 8; ++j) t[j] = (__bf16)((float)t[j] * 0.125f);
            qf[s][kh] = t;
        }

    f32x4 ot[2][4] = {};
    float m_i[2] = {-INFINITY, -INFINITY};
    float l_i[2] = {0.f, 0.f};

    const int qmax_w = q0 + w * 32 + 31;
    const int ktmax  = (q0 + 127) >> 6;     // 2qt+1

    bf16x8 kr0, kr1, vr0, vr1;
    {
        const int k0 = 0;
        kr0 = *(const bf16x8*)&qkv[base + (size_t)(k0 + krow0) * rs + HH + kc0];
        kr1 = *(const bf16x8*)&qkv[base + (size_t)(k0 + krow1) * rs + HH + kc1];
        vr0 = *(const bf16x8*)&qkv[base + (size_t)(k0 + vkey) * rs + 2 * HH + vcb0];
        vr1 = *(const bf16x8*)&qkv[base + (size_t)(k0 + vkey) * rs + 2 * HH + vcb1];
        *(bf16x8*)&Ks[0][krow0 * 72 + kc0] = kr0;
        *(bf16x8*)&Ks[0][krow1 * 72 + kc1] = kr1;
#pragma unroll
        for (int j = 0; j < 8; ++j) Vt[0][(vcb0 + j) * 72 + vkey] = vr0[j];
#pragma unroll
        for (int j = 0; j < 8; ++j) Vt[0][(vcb1 + j) * 72 + vkey] = vr1[j];
    }
    __syncthreads();

    for (int kt = 0; kt <= ktmax; ++kt) {
        const int k0  = kt << 6;
        const int buf = kt & 1;

        if (kt < ktmax) {
            const int kn = k0 + 64;
            kr0 = *(const bf16x8*)&qkv[base + (size_t)(kn + krow0) * rs + HH + kc0];
            kr1 = *(const bf16x8*)&qkv[base + (size_t)(kn + krow1) * rs + HH + kc1];
            vr0 = *(const bf16x8*)&qkv[base + (size_t)(kn + vkey) * rs + 2 * HH + vcb0];
            vr1 = *(const bf16x8*)&qkv[base + (size_t)(kn + vkey) * rs + 2 * HH + vcb1];
        }

        if (k0 <= qmax_w) {
#pragma unroll
            for (int s = 0; s < 2; ++s) {
                f32x4 st[4] = {};
                __builtin_amdgcn_s_setprio(1);
#pragma unroll
                for (int kh = 0; kh < 2; ++kh)
#pragma unroll
                    for (int m = 0; m < 4; ++m) {
                        bf16x8 kf = *(const bf16x8*)&Ks[buf][(m * 16 + lm) * 72 + kh * 32 + kq * 8];
                        st[m] = __builtin_amdgcn_mfma_f32_16x16x32_bf16(
                            kf, qf[s][kh], st[m], 0, 0, 0);
                    }
                __builtin_amdgcn_s_setprio(0);

                const int qg = q0 + w * 32 + s * 16 + lm;
                if (k0 + 63 > q0 + w * 32 + s * 16) {
#pragma unroll
                    for (int m = 0; m < 4; ++m) {
                        int keyb = k0 + m * 16 + kq * 4;
#pragma unroll
                        for (int r = 0; r < 4; ++r)
                            if (keyb + r > qg) st[m][r] = -INFINITY;
                    }
                }

                float mloc = -INFINITY;
#pragma unroll
                for (int m = 0; m < 4; ++m)
#pragma unroll
                    for (int r = 0; r < 4; ++r) mloc = fmaxf(mloc, st[m][r]);
                mloc = fmaxf(mloc, __shfl_xor(mloc, 16));
                mloc = fmaxf(mloc, __shfl_xor(mloc, 32));
                float mn    = fmaxf(m_i[s], mloc);
                float alpha = __expf(m_i[s] - mn);
                m_i[s] = mn;

                float sum = 0.f;
#pragma unroll
                for (int m = 0; m < 4; ++m) {
                    bf16x4 pb;
#pragma unroll
                    for (int r = 0; r < 4; ++r) {
                        float p = __expf(st[m][r] - mn);
                        sum += p;
                        pb[r] = (__bf16)p;
                    }
                    *(bf16x4*)&Ps[w][s][lm * 72 + m * 16 + kq * 4] = pb;
                }
                sum += __shfl_xor(sum, 16);
                sum += __shfl_xor(sum, 32);
                l_i[s] = l_i[s] * alpha + sum;

#pragma unroll
                for (int dt = 0; dt < 4; ++dt) ot[s][dt] *= alpha;

                __builtin_amdgcn_s_setprio(1);
#pragma unroll
                for (int kh = 0; kh < 2; ++kh) {
                    bf16x8 pf = *(const bf16x8*)&Ps[w][s][lm * 72 + kh * 32 + kq * 8];
#pragma unroll
                    for (int dt = 0; dt < 4; ++dt) {
                        bf16x8 vf = *(const bf16x8*)&Vt[buf][(dt * 16 + lm) * 72 + kh * 32 + kq * 8];
                        ot[s][dt] = __builtin_amdgcn_mfma_f32_16x16x32_bf16(
                            vf, pf, ot[s][dt], 0, 0, 0);
                    }
                }
                __builtin_amdgcn_s_setprio(0);
            }
        }

        if (kt < ktmax) {
            const int nb = buf ^ 1;
            *(bf16x8*)&Ks[nb][krow0 * 72 + kc0] = kr0;
            *(bf16x8*)&Ks[nb][krow1 * 72 + kc1] = kr1;
#pragma unroll
            for (int j = 0; j < 8; ++j) Vt[nb][(vcb0 + j) * 72 + vkey] = vr0[j];
#pragma unroll
            for (int j = 0; j < 8; ++j) Vt[nb][(vcb1 + j) * 72 + vkey] = vr1[j];
            __syncthreads();
        }
    }

#pragma unroll
    for (int s = 0; s < 2; ++s) {
        float inv = 1.f / l_i[s];
        int qg = q0 + w * 32 + s * 16 + lm;
#pragma unroll
        for (int dt = 0; dt < 4; ++dt) {
            bf16x4 ob;
#pragma unroll
            for (int r = 0; r < 4; ++r) ob[r] = (__bf16)(ot[s][dt][r] * inv);
            *(bf16x4*)&out[(size_t)(b * SS + qg) * HH + h * HDD + dt * 16 + kq * 4] = ob;
        }
    }
}

// ---------------------------------------------------------------------------
extern "C" void kernel_launch(void* const* d_in, const int* in_sizes, int n_in,
                              void* d_out, int out_size, void* d_ws, size_t ws_size,
                              hipStream_t stream) {
    const float* hidden = (const float*)d_in[0];
    const float* ln1_g  = (const float*)d_in[1];
    const float* ln1_b  = (const float*)d_in[2];
    const float* Wqkv   = (const float*)d_in[3];
    const float* Wproj  = (const float*)d_in[4];
    const float* ln2_g  = (const float*)d_in[5];
    const float* ln2_b  = (const float*)d_in[6];
    const float* Wfc1   = (const float*)d_in[7];
    const float* Wfc2   = (const float*)d_in[8];
    const float* lnf_g  = (const float*)d_in[9];
    const float* lnf_b  = (const float*)d_in[10];

    float* x = (float*)d_out;              // residual stream (fp32) in d_out

    char* p = (char*)d_ws;
    __hip_bfloat16* hbuf  = (__hip_bfloat16*)p; p += (size_t)BS * HH * 2;
    __hip_bfloat16* qkvb  = (__hip_bfloat16*)p; p += (size_t)BS * 3 * HH * 2;
    __hip_bfloat16* attnb = (__hip_bfloat16*)p; p += (size_t)BS * HH * 2;
    __hip_bfloat16* ffnb  = (__hip_bfloat16*)p; p += (size_t)BS * FFN_ * 2;
    __hip_bfloat16* wqkvT = (__hip_bfloat16*)p; p += (size_t)3 * HH * HH * 2;
    __hip_bfloat16* wprojT= (__hip_bfloat16*)p; p += (size_t)HH * HH * 2;
    __hip_bfloat16* wfc1T = (__hip_bfloat16*)p; p += (size_t)FFN_ * HH * 2;
    __hip_bfloat16* wfc2T = (__hip_bfloat16*)p; p += (size_t)HH * FFN_ * 2;

    hipMemcpyAsync(x, hidden, (size_t)BS * HH * sizeof(float),
                   hipMemcpyDeviceToDevice, stream);

    const int NBY = BS / 128;   // 32

    for (int lyr = 0; lyr < LYRS; ++lyr) {
        transpose_all<<<12288, 256, 0, stream>>>(
            Wqkv  + (size_t)lyr * HH * 3 * HH,
            Wproj + (size_t)lyr * HH * HH,
            Wfc1  + (size_t)lyr * HH * FFN_,
            Wfc2  + (size_t)lyr * FFN_ * HH,
            wqkvT, wprojT, wfc1T, wfc2T);

        ln_w<__hip_bfloat16><<<BS / 4, 256, 0, stream>>>(
            x, ln1_g + lyr * HH, ln1_b + lyr * HH, hbuf);
        // qkv: 128^2, 768 blocks (3 blocks/CU)
        gemm_bf16<false, false, 1, __hip_bfloat16>
            <<<(3 * HH / 128) * NBY, 256, 0, stream>>>(
            hbuf, wqkvT, nullptr, qkvb, BS, 3 * HH, HH);
        attn_fa3<<<512, 256, 0, stream>>>((const __bf16*)qkvb, (__bf16*)attnb);
        // proj: split-K=2 (512 blocks, 2/CU); x holds residual, atomics add in
        gemm_bf16<false, false, 2, float>
            <<<(HH / 128) * NBY * 2, 256, 0, stream>>>(
            attnb, wprojT, nullptr, x, BS, HH, HH);
        ln_w<__hip_bfloat16><<<BS / 4, 256, 0, stream>>>(
            x, ln2_g + lyr * HH, ln2_b + lyr * HH, hbuf);
        // fc1: 128^2, 1024 blocks (4 blocks/CU)
        gemm_bf16<true, false, 1, __hip_bfloat16>
            <<<(FFN_ / 128) * NBY, 256, 0, stream>>>(
            hbuf, wfc1T, nullptr, ffnb, BS, FFN_, HH);
        // fc2: split-K=2 (512 blocks, 2/CU); atomics into x
        gemm_bf16<false, false, 2, float>
            <<<(HH / 128) * NBY * 2, 256, 0, stream>>>(
            ffnb, wfc2T, nullptr, x, BS, HH, FFN_);
    }
    ln_w<float><<<BS / 4, 256, 0, stream>>>(x, lnf_g, lnf_b, x);
}

// Round 5
// 1254.321 us; speedup vs baseline: 1.2104x; 1.0496x over previous
//
#include <hip/hip_runtime.h>
#include <hip/hip_bf16.h>
#include <math.h>

// Problem constants
#define LYRS 4
#define BB   2
#define SS   2048
#define HH   1024
#define NHD  16
#define HDD  64
#define FFN_ 4096
#define BS   (BB*SS)          // 4096 rows
#define EPS_ 1e-5f

typedef __attribute__((ext_vector_type(8))) __bf16 bf16x8;
typedef __attribute__((ext_vector_type(4))) __bf16 bf16x4;
typedef __attribute__((ext_vector_type(4))) float f32x4;
typedef __attribute__((address_space(1))) void* gas_t;
typedef __attribute__((address_space(3))) void* las_t;

__device__ inline void async16(void* lds, const void* g) {
    __builtin_amdgcn_global_load_lds((gas_t)g, (las_t)lds, 16, 0, 0);
}

__device__ inline void storev(float* p, float v) { *p = v; }
__device__ inline void storev(__hip_bfloat16* p, float v) { *p = __float2bfloat16(v); }

__device__ inline void store4(float* p, float a, float b, float c, float d) {
    *(float4*)p = make_float4(a, b, c, d);
}
__device__ inline void store4(__hip_bfloat16* p, float a, float b, float c, float d) {
    bf16x4 t; t[0] = (__bf16)a; t[1] = (__bf16)b; t[2] = (__bf16)c; t[3] = (__bf16)d;
    *(bf16x4*)p = t;
}

// Exact-GELU via Abramowitz-Stegun 7.1.26 erf (max err 1.5e-7 — invisible
// under bf16 output rounding). Avoids libm erff codegen variance.
__device__ inline float gelu_f(float v) {
    const float z = fabsf(v) * 0.70710678118654752f;
    const float t = 1.0f / (1.0f + 0.3275911f * z);
    const float p = t * (0.254829592f + t * (-0.284496736f +
                    t * (1.421413741f + t * (-1.453152027f + t * 1.061405429f))));
    const float e = p * __expf(-z * z);            // = 1 - erf(z), z >= 0
    return v * (v >= 0.f ? (1.0f - 0.5f * e) : (0.5f * e));
}

// ---------------- LayerNorm: one WAVE per row of H=1024 ---------------------
template <typename OutT>
__global__ __launch_bounds__(256) void ln_w(const float* __restrict__ x,
                                            const float* __restrict__ g,
                                            const float* __restrict__ b,
                                            OutT* __restrict__ y) {
    const int row  = blockIdx.x * 4 + (threadIdx.x >> 6);
    const int lane = threadIdx.x & 63;
    const float4* xr = (const float4*)(x + (size_t)row * HH);

    float4 v[4];
    float s = 0.f, s2 = 0.f;
#pragma unroll
    for (int i = 0; i < 4; ++i) {
        v[i] = xr[lane + i * 64];
        s  += v[i].x + v[i].y + v[i].z + v[i].w;
        s2 += v[i].x * v[i].x + v[i].y * v[i].y + v[i].z * v[i].z + v[i].w * v[i].w;
    }
#pragma unroll
    for (int o = 1; o < 64; o <<= 1) {
        s  += __shfl_xor(s,  o);
        s2 += __shfl_xor(s2, o);
    }
    const float mu   = s * (1.f / HH);
    const float rstd = rsqrtf(s2 * (1.f / HH) - mu * mu + EPS_);
#pragma unroll
    for (int i = 0; i < 4; ++i) {
        const int c = (lane + i * 64) * 4;
        const float4 gv = *(const float4*)&g[c];
        const float4 bv = *(const float4*)&b[c];
        store4(&y[(size_t)row * HH + c],
               (v[i].x - mu) * rstd * gv.x + bv.x,
               (v[i].y - mu) * rstd * gv.y + bv.y,
               (v[i].z - mu) * rstd * gv.z + bv.z,
               (v[i].w - mu) * rstd * gv.w + bv.w);
    }
}

// ---------------- batched transpose+cast: all 4 weights of one layer --------
__global__ __launch_bounds__(256) void transpose_all(
    const float* __restrict__ Wqkv_l, const float* __restrict__ Wproj_l,
    const float* __restrict__ Wfc1_l, const float* __restrict__ Wfc2_l,
    __hip_bfloat16* __restrict__ wqkvT, __hip_bfloat16* __restrict__ wprojT,
    __hip_bfloat16* __restrict__ wfc1T, __hip_bfloat16* __restrict__ wfc2T)
{
    __shared__ float t[32][33];
    int tb = blockIdx.x;
    const float* W; __hip_bfloat16* WT; int K, N, nx;
    if (tb < 3072)      {            W = Wqkv_l;  WT = wqkvT;  K = HH;   N = 3 * HH; nx = 96;  }
    else if (tb < 4096) { tb -= 3072; W = Wproj_l; WT = wprojT; K = HH;   N = HH;     nx = 32;  }
    else if (tb < 8192) { tb -= 4096; W = Wfc1_l;  WT = wfc1T;  K = HH;   N = FFN_;   nx = 128; }
    else                { tb -= 8192; W = Wfc2_l;  WT = wfc2T;  K = FFN_; N = HH;     nx = 32;  }
    const int n0 = (tb % nx) * 32, k0 = (tb / nx) * 32;
    const int tx = threadIdx.x & 31, ty8 = threadIdx.x >> 5;
#pragma unroll
    for (int i = 0; i < 4; ++i) {
        int k = ty8 + i * 8;
        t[k][tx] = W[(size_t)(k0 + k) * N + n0 + tx];
    }
    __syncthreads();
#pragma unroll
    for (int i = 0; i < 4; ++i) {
        int n = ty8 + i * 8;
        WT[(size_t)(n0 + n) * K + k0 + tx] = __float2bfloat16(t[tx][n]);
    }
}

// ---------------- 128x128 bf16 MFMA GEMM (4 waves, 2-phase dbuf) ------------
// Round-1-proven K-loop. XCD-chunked bijective bid swizzle (T1): each XCD
// gets a contiguous tile range -> its B-panels stay resident in the private
// L2 -> staged loads hit L2 -> shorter per-step drains. Grids are %8==0.
// SPLITK>1: fp32 partials atomicAdd'ed into C (caller: C holds residual).
template <bool GELU, bool RES, int SPLITK, typename OutT>
__global__ __launch_bounds__(256) void gemm_bf16(
    const __hip_bfloat16* __restrict__ A,    // [M,K] row-major
    const __hip_bfloat16* __restrict__ BT,   // [N,K] row-major (= B^T)
    const float* __restrict__ R,             // residual [M,N] fp32 (or null)
    OutT* __restrict__ C,                    // [M,N]
    int M, int N, int K)
{
    __shared__ unsigned short As[2][128 * 32];
    __shared__ unsigned short Bs[2][128 * 32];

    const int tid  = threadIdx.x;
    const int lane = tid & 63;
    const int wv   = tid >> 6;               // 0..3
    const int wy   = wv >> 1, wx = wv & 1;   // 2x2 wave grid (64x64 each)

    // XCD swizzle: orig%8 = XCD (round-robin dispatch) -> give each XCD a
    // contiguous chunk of the tile space. Bijective since gridDim.x % 8 == 0.
    const int cpx = gridDim.x >> 3;
    const int bid = (blockIdx.x & 7) * cpx + (blockIdx.x >> 3);

    const int nby  = M >> 7;                 // 32
    const int tiles = nby * (N >> 7);
    const int ks   = bid / tiles;            // K-slice (0 if SPLITK==1)
    const int rem  = bid % tiles;
    const int by   = rem % nby;
    const int bx   = rem / nby;
    const int row0 = by * 128;
    const int col0 = bx * 128;
    const int lm   = lane & 15;
    const int kq   = lane >> 4;

    const int Kslice = K / SPLITK;
    const int kbeg   = ks * Kslice;
    const int nsteps = Kslice >> 5;

    const unsigned short* Ag = (const unsigned short*)A;
    const unsigned short* Bg = (const unsigned short*)BT;

    const int li0 = tid, li1 = 256 + tid;
    const int r0 = li0 >> 2, c0 = (li0 & 3) << 3;
    const int r1 = li1 >> 2, c1 = (li1 & 3) << 3;
    const unsigned short* Ag0 = Ag + (size_t)(row0 + r0) * K + c0;
    const unsigned short* Ag1 = Ag + (size_t)(row0 + r1) * K + c1;
    const unsigned short* Bg0 = Bg + (size_t)(col0 + r0) * K + c0;
    const unsigned short* Bg1 = Bg + (size_t)(col0 + r1) * K + c1;

    auto stage = [&](int buf, int k) {
        async16(&As[buf][li0 * 8], Ag0 + k);
        async16(&As[buf][li1 * 8], Ag1 + k);
        async16(&Bs[buf][li0 * 8], Bg0 + k);
        async16(&Bs[buf][li1 * 8], Bg1 + k);
    };

    f32x4 acc[4][4] = {};

    stage(0, kbeg);
    __syncthreads();                         // tile 0 ready

    for (int s = 0; s < nsteps; ++s) {
        const int buf = s & 1;
        if (s + 1 < nsteps) stage(buf ^ 1, kbeg + ((s + 1) << 5));

        bf16x8 af[4], bfr[4];
#pragma unroll
        for (int i = 0; i < 4; ++i)
            af[i] = *(const bf16x8*)&As[buf][(wy * 64 + i * 16 + lm) * 32 + kq * 8];
#pragma unroll
        for (int j = 0; j < 4; ++j)
            bfr[j] = *(const bf16x8*)&Bs[buf][(wx * 64 + j * 16 + lm) * 32 + kq * 8];
#pragma unroll
        for (int i = 0; i < 4; ++i)
#pragma unroll
            for (int j = 0; j < 4; ++j)
                acc[i][j] = __builtin_amdgcn_mfma_f32_16x16x32_bf16(
                    af[i], bfr[j], acc[i][j], 0, 0, 0);

        __syncthreads();   // my reads done + next tile landed
    }

#pragma unroll
    for (int i = 0; i < 4; ++i) {
#pragma unroll
        for (int j = 0; j < 4; ++j) {
            int gc = col0 + wx * 64 + j * 16 + lm;
#pragma unroll
            for (int r = 0; r < 4; ++r) {
                int gr = row0 + wy * 64 + i * 16 + kq * 4 + r;
                float v = acc[i][j][r];
                if constexpr (SPLITK > 1) {
                    atomicAdd((float*)&C[(size_t)gr * N + gc], v);
                } else {
                    if (RES)  v += R[(size_t)gr * N + gc];
                    if (GELU) v = gelu_f(v);
                    storev(&C[(size_t)gr * N + gc], v);
                }
            }
        }
    }
}

// ---------------- MFMA causal flash attention (double-buffered) -------------
// Block = 128 queries x 1 head, 256 thr (4 waves x 2 slabs of 16 q).
// setprio(1) around both MFMA clusters (T5: measured +4-7% on attn, m191).
__global__ __launch_bounds__(256) void attn_fa3(const __bf16* __restrict__ qkv,
                                                __bf16* __restrict__ out) {
    __shared__ __bf16 Ks[2][64 * 72];       // K[key][d], stride 72
    __shared__ __bf16 Vt[2][64 * 72];       // V^T[d][key], stride 72
    __shared__ __bf16 Ps[4][2][16 * 72];    // per wave/slab: P[q][key]

    const int tid  = threadIdx.x;
    const int lane = tid & 63;
    const int w    = tid >> 6;              // wave 0..3
    const int lm   = lane & 15;
    const int kq   = lane >> 4;

    const int x  = blockIdx.x;
    const int bh = x & 31;
    const int h  = bh & 15;
    const int b  = bh >> 4;
    const int a  = (x >> 5) & 7;
    const int qt = (x & 256) ? (15 - a) : a;
    const int q0 = qt * 128;

    const size_t rs   = 3 * HH;
    const size_t base = (size_t)b * SS * rs + (size_t)h * HDD;

    const int krow0 = tid >> 3,        kc0 = (tid & 7) << 3;          // it=0
    const int krow1 = (256 + tid) >> 3, kc1 = ((256 + tid) & 7) << 3; // it=1
    const int vkey  = tid & 63;
    const int vcb0  = (tid >> 6) << 3, vcb1 = ((256 + tid) >> 6) << 3;

    bf16x8 qf[2][2];
#pragma unroll
    for (int s = 0; s < 2; ++s)
#pragma unroll
        for (int kh = 0; kh < 2; ++kh) {
            bf16x8 t = *(const bf16x8*)&qkv[base +
                (size_t)(q0 + w * 32 + s * 16 + lm) * rs + kh * 32 + kq * 8];
#pragma unroll
            for (int j = 0; j < 8; ++j) t[j] = (__bf16)((float)t[j] * 0.125f);
            qf[s][kh] = t;
        }

    f32x4 ot[2][4] = {};
    float m_i[2] = {-INFINITY, -INFINITY};
    float l_i[2] = {0.f, 0.f};

    const int qmax_w = q0 + w * 32 + 31;
    const int ktmax  = (q0 + 127) >> 6;     // 2qt+1

    bf16x8 kr0, kr1, vr0, vr1;
    {
        const int k0 = 0;
        kr0 = *(const bf16x8*)&qkv[base + (size_t)(k0 + krow0) * rs + HH + kc0];
        kr1 = *(const bf16x8*)&qkv[base + (size_t)(k0 + krow1) * rs + HH + kc1];
        vr0 = *(const bf16x8*)&qkv[base + (size_t)(k0 + vkey) * rs + 2 * HH + vcb0];
        vr1 = *(const bf16x8*)&qkv[base + (size_t)(k0 + vkey) * rs + 2 * HH + vcb1];
        *(bf16x8*)&Ks[0][krow0 * 72 + kc0] = kr0;
        *(bf16x8*)&Ks[0][krow1 * 72 + kc1] = kr1;
#pragma unroll
        for (int j = 0; j < 8; ++j) Vt[0][(vcb0 + j) * 72 + vkey] = vr0[j];
#pragma unroll
        for (int j = 0; j < 8; ++j) Vt[0][(vcb1 + j) * 72 + vkey] = vr1[j];
    }
    __syncthreads();

    for (int kt = 0; kt <= ktmax; ++kt) {
        const int k0  = kt << 6;
        const int buf = kt & 1;

        if (kt < ktmax) {
            const int kn = k0 + 64;
            kr0 = *(const bf16x8*)&qkv[base + (size_t)(kn + krow0) * rs + HH + kc0];
            kr1 = *(const bf16x8*)&qkv[base + (size_t)(kn + krow1) * rs + HH + kc1];
            vr0 = *(const bf16x8*)&qkv[base + (size_t)(kn + vkey) * rs + 2 * HH + vcb0];
            vr1 = *(const bf16x8*)&qkv[base + (size_t)(kn + vkey) * rs + 2 * HH + vcb1];
        }

        if (k0 <= qmax_w) {
#pragma unroll
            for (int s = 0; s < 2; ++s) {
                f32x4 st[4] = {};
                __builtin_amdgcn_s_setprio(1);
#pragma unroll
                for (int kh = 0; kh < 2; ++kh)
#pragma unroll
                    for (int m = 0; m < 4; ++m) {
                        bf16x8 kf = *(const bf16x8*)&Ks[buf][(m * 16 + lm) * 72 + kh * 32 + kq * 8];
                        st[m] = __builtin_amdgcn_mfma_f32_16x16x32_bf16(
                            kf, qf[s][kh], st[m], 0, 0, 0);
                    }
                __builtin_amdgcn_s_setprio(0);

                const int qg = q0 + w * 32 + s * 16 + lm;
                if (k0 + 63 > q0 + w * 32 + s * 16) {
#pragma unroll
                    for (int m = 0; m < 4; ++m) {
                        int keyb = k0 + m * 16 + kq * 4;
#pragma unroll
                        for (int r = 0; r < 4; ++r)
                            if (keyb + r > qg) st[m][r] = -INFINITY;
                    }
                }

                float mloc = -INFINITY;
#pragma unroll
                for (int m = 0; m < 4; ++m)
#pragma unroll
                    for (int r = 0; r < 4; ++r) mloc = fmaxf(mloc, st[m][r]);
                mloc = fmaxf(mloc, __shfl_xor(mloc, 16));
                mloc = fmaxf(mloc, __shfl_xor(mloc, 32));
                float mn    = fmaxf(m_i[s], mloc);
                float alpha = __expf(m_i[s] - mn);
                m_i[s] = mn;

                float sum = 0.f;
#pragma unroll
                for (int m = 0; m < 4; ++m) {
                    bf16x4 pb;
#pragma unroll
                    for (int r = 0; r < 4; ++r) {
                        float p = __expf(st[m][r] - mn);
                        sum += p;
                        pb[r] = (__bf16)p;
                    }
                    *(bf16x4*)&Ps[w][s][lm * 72 + m * 16 + kq * 4] = pb;
                }
                sum += __shfl_xor(sum, 16);
                sum += __shfl_xor(sum, 32);
                l_i[s] = l_i[s] * alpha + sum;

#pragma unroll
                for (int dt = 0; dt < 4; ++dt) ot[s][dt] *= alpha;

                __builtin_amdgcn_s_setprio(1);
#pragma unroll
                for (int kh = 0; kh < 2; ++kh) {
                    bf16x8 pf = *(const bf16x8*)&Ps[w][s][lm * 72 + kh * 32 + kq * 8];
#pragma unroll
                    for (int dt = 0; dt < 4; ++dt) {
                        bf16x8 vf = *(const bf16x8*)&Vt[buf][(dt * 16 + lm) * 72 + kh * 32 + kq * 8];
                        ot[s][dt] = __builtin_amdgcn_mfma_f32_16x16x32_bf16(
                            vf, pf, ot[s][dt], 0, 0, 0);
                    }
                }
                __builtin_amdgcn_s_setprio(0);
            }
        }

        if (kt < ktmax) {
            const int nb = buf ^ 1;
            *(bf16x8*)&Ks[nb][krow0 * 72 + kc0] = kr0;
            *(bf16x8*)&Ks[nb][krow1 * 72 + kc1] = kr1;
#pragma unroll
            for (int j = 0; j < 8; ++j) Vt[nb][(vcb0 + j) * 72 + vkey] = vr0[j];
#pragma unroll
            for (int j = 0; j < 8; ++j) Vt[nb][(vcb1 + j) * 72 + vkey] = vr1[j];
            __syncthreads();
        }
    }

#pragma unroll
    for (int s = 0; s < 2; ++s) {
        float inv = 1.f / l_i[s];
        int qg = q0 + w * 32 + s * 16 + lm;
#pragma unroll
        for (int dt = 0; dt < 4; ++dt) {
            bf16x4 ob;
#pragma unroll
            for (int r = 0; r < 4; ++r) ob[r] = (__bf16)(ot[s][dt][r] * inv);
            *(bf16x4*)&out[(size_t)(b * SS + qg) * HH + h * HDD + dt * 16 + kq * 4] = ob;
        }
    }
}

// ---------------------------------------------------------------------------
extern "C" void kernel_launch(void* const* d_in, const int* in_sizes, int n_in,
                              void* d_out, int out_size, void* d_ws, size_t ws_size,
                              hipStream_t stream) {
    const float* hidden = (const float*)d_in[0];
    const float* ln1_g  = (const float*)d_in[1];
    const float* ln1_b  = (const float*)d_in[2];
    const float* Wqkv   = (const float*)d_in[3];
    const float* Wproj  = (const float*)d_in[4];
    const float* ln2_g  = (const float*)d_in[5];
    const float* ln2_b  = (const float*)d_in[6];
    const float* Wfc1   = (const float*)d_in[7];
    const float* Wfc2   = (const float*)d_in[8];
    const float* lnf_g  = (const float*)d_in[9];
    const float* lnf_b  = (const float*)d_in[10];

    float* x = (float*)d_out;              // residual stream (fp32) in d_out

    char* p = (char*)d_ws;
    __hip_bfloat16* hbuf  = (__hip_bfloat16*)p; p += (size_t)BS * HH * 2;
    __hip_bfloat16* qkvb  = (__hip_bfloat16*)p; p += (size_t)BS * 3 * HH * 2;
    __hip_bfloat16* attnb = (__hip_bfloat16*)p; p += (size_t)BS * HH * 2;
    __hip_bfloat16* ffnb  = (__hip_bfloat16*)p; p += (size_t)BS * FFN_ * 2;
    __hip_bfloat16* wqkvT = (__hip_bfloat16*)p; p += (size_t)3 * HH * HH * 2;
    __hip_bfloat16* wprojT= (__hip_bfloat16*)p; p += (size_t)HH * HH * 2;
    __hip_bfloat16* wfc1T = (__hip_bfloat16*)p; p += (size_t)FFN_ * HH * 2;
    __hip_bfloat16* wfc2T = (__hip_bfloat16*)p; p += (size_t)HH * FFN_ * 2;

    hipMemcpyAsync(x, hidden, (size_t)BS * HH * sizeof(float),
                   hipMemcpyDeviceToDevice, stream);

    const int NBY = BS / 128;   // 32

    for (int lyr = 0; lyr < LYRS; ++lyr) {
        transpose_all<<<12288, 256, 0, stream>>>(
            Wqkv  + (size_t)lyr * HH * 3 * HH,
            Wproj + (size_t)lyr * HH * HH,
            Wfc1  + (size_t)lyr * HH * FFN_,
            Wfc2  + (size_t)lyr * FFN_ * HH,
            wqkvT, wprojT, wfc1T, wfc2T);

        ln_w<__hip_bfloat16><<<BS / 4, 256, 0, stream>>>(
            x, ln1_g + lyr * HH, ln1_b + lyr * HH, hbuf);
        // qkv: 128^2, 768 blocks (3 blocks/CU)
        gemm_bf16<false, false, 1, __hip_bfloat16>
            <<<(3 * HH / 128) * NBY, 256, 0, stream>>>(
            hbuf, wqkvT, nullptr, qkvb, BS, 3 * HH, HH);
        attn_fa3<<<512, 256, 0, stream>>>((const __bf16*)qkvb, (__bf16*)attnb);
        // proj: round-1 form — residual read + store (restores instantiation set)
        gemm_bf16<false, true, 1, float>
            <<<(HH / 128) * NBY, 256, 0, stream>>>(
            attnb, wprojT, x, x, BS, HH, HH);
        ln_w<__hip_bfloat16><<<BS / 4, 256, 0, stream>>>(
            x, ln2_g + lyr * HH, ln2_b + lyr * HH, hbuf);
        // fc1: 128^2, 1024 blocks (4 blocks/CU)
        gemm_bf16<true, false, 1, __hip_bfloat16>
            <<<(FFN_ / 128) * NBY, 256, 0, stream>>>(
            hbuf, wfc1T, nullptr, ffnb, BS, FFN_, HH);
        // fc2: split-K=2 (512 blocks, 2/CU); x holds residual, atomics add in
        gemm_bf16<false, false, 2, float>
            <<<(HH / 128) * NBY * 2, 256, 0, stream>>>(
            ffnb, wfc2T, nullptr, x, BS, HH, FFN_);
    }
    ln_w<float><<<BS / 4, 256, 0, stream>>>(x, lnf_g, lnf_b, x);
}